// Round 1
// baseline (1854.451 us; speedup 1.0000x reference)
//
#include <hip/hip_runtime.h>
#include <stdint.h>

#define N_TOKENS 16384
#define HIDDEN   1024
#define FFN      4096
#define N_EXPERTS 8
#define MAX_TILES 264            // worst-case padded 128-row tiles (sum<=263)
#define HALF_TILES 132
#define MAX_ROWS (MAX_TILES * 128)   // 33792
#define HALF_ROWS (HALF_TILES * 128) // 16896

typedef __attribute__((ext_vector_type(8))) short short8;
typedef __attribute__((ext_vector_type(4))) float f32x4;

// meta layout (ints): [0..7] counts, [8..15] cursors, [16..24] offs, [25] ntiles

__device__ inline unsigned short f2bf(float f) {
  union { float f; unsigned u; } c; c.f = f;
  unsigned u = c.u;
  unsigned r = (u + 0x7fffu + ((u >> 16) & 1u)) >> 16;  // RNE
  return (unsigned short)r;
}

__device__ inline void gld_lds16(const unsigned short* g, unsigned short* l) {
  __builtin_amdgcn_global_load_lds(
      (const __attribute__((address_space(1))) void*)g,
      (__attribute__((address_space(3))) void*)l, 16, 0, 0);
}

// ---------------- gate: scores, top-2, softmax, counts ----------------
__global__ __launch_bounds__(256) void gate_kernel(
    const float* __restrict__ x, const float* __restrict__ Wg,
    const float* __restrict__ bg, int* __restrict__ gate_idx,
    float* __restrict__ gate_w, int* __restrict__ meta)
{
  int lane = threadIdx.x & 63;
  int wv = threadIdx.x >> 6;
  int t = blockIdx.x * 4 + wv;
  const float* xr = x + (size_t)t * HIDDEN;
  float acc[N_EXPERTS];
#pragma unroll
  for (int e = 0; e < N_EXPERTS; e++) acc[e] = 0.f;
#pragma unroll
  for (int i = 0; i < HIDDEN / 64; i++) {
    int h = i * 64 + lane;
    float xv = xr[h];
    const float4* wv4 = (const float4*)(Wg + (size_t)h * N_EXPERTS);
    float4 w01 = wv4[0], w23 = wv4[1];
    acc[0] = fmaf(xv, w01.x, acc[0]); acc[1] = fmaf(xv, w01.y, acc[1]);
    acc[2] = fmaf(xv, w01.z, acc[2]); acc[3] = fmaf(xv, w01.w, acc[3]);
    acc[4] = fmaf(xv, w23.x, acc[4]); acc[5] = fmaf(xv, w23.y, acc[5]);
    acc[6] = fmaf(xv, w23.z, acc[6]); acc[7] = fmaf(xv, w23.w, acc[7]);
  }
#pragma unroll
  for (int off = 32; off > 0; off >>= 1)
#pragma unroll
    for (int e = 0; e < N_EXPERTS; e++)
      acc[e] += __shfl_down(acc[e], off, 64);
  if (lane == 0) {
    float s[N_EXPERTS];
#pragma unroll
    for (int e = 0; e < N_EXPERTS; e++) s[e] = acc[e] + bg[e];
    int e0 = 0;
#pragma unroll
    for (int e = 1; e < N_EXPERTS; e++) if (s[e] > s[e0]) e0 = e;  // ties -> lowest idx
    int e1 = (e0 == 0) ? 1 : 0;
#pragma unroll
    for (int e = 0; e < N_EXPERTS; e++) if (e != e0 && s[e] > s[e1]) e1 = e;
    float d = s[e1] - s[e0];          // <= 0
    float ex = __expf(d);
    float w0 = 1.f / (1.f + ex);
    float w1 = ex / (1.f + ex);
    gate_idx[2 * t] = e0; gate_idx[2 * t + 1] = e1;
    gate_w[2 * t] = w0;  gate_w[2 * t + 1] = w1;
    atomicAdd(&meta[e0], 1);
    atomicAdd(&meta[e1], 1);
  }
}

// ---------------- 128-aligned per-expert offsets ----------------
__global__ void offsets_kernel(int* meta)
{
  if (threadIdx.x == 0) {
    int off = 0;
    for (int e = 0; e < N_EXPERTS; e++) {
      meta[16 + e] = off;
      off += ((meta[e] + 127) >> 7) << 7;
    }
    meta[16 + N_EXPERTS] = off;
    meta[25] = off >> 7;
  }
}

// ---------------- route: fill pair lists, grouped by expert ----------------
__global__ __launch_bounds__(256) void route_kernel(
    const int* __restrict__ gate_idx, const float* __restrict__ gate_w,
    int* __restrict__ meta, int* __restrict__ pair_token,
    float* __restrict__ pair_w)
{
  int t = blockIdx.x * 256 + threadIdx.x;
  int lane = threadIdx.x & 63;
  const int* offs = meta + 16;
  int* cursors = meta + 8;
#pragma unroll
  for (int k = 0; k < 2; k++) {
    int e = gate_idx[2 * t + k];
    float w = gate_w[2 * t + k];
    int pos = 0;
    for (int ee = 0; ee < N_EXPERTS; ee++) {
      unsigned long long m = __ballot(e == ee);
      int leader = __ffsll((unsigned long long)m) - 1;  // -1 if empty
      int base = 0;
      if (e == ee && lane == leader)
        base = atomicAdd(&cursors[ee], __popcll(m));
      base = __shfl(base, leader >= 0 ? leader : 0, 64);  // all lanes participate
      if (e == ee)
        pos = base + __popcll(m & ((1ull << lane) - 1ull));
    }
    int row = offs[e] + pos;
    pair_token[row] = t;
    pair_w[row] = w;
  }
}

// ---------------- gather x rows -> bf16 Xg (grouped rows) ----------------
__global__ __launch_bounds__(256) void gather_kernel(
    const float* __restrict__ x, const int* __restrict__ pair_token,
    unsigned short* __restrict__ Xg)
{
  int r = blockIdx.x;
  int t = pair_token[r];
  if (t < 0) return;  // pad row: left as poison; dropped at GEMM2 epilogue
  const float4* src = (const float4*)(x + (size_t)t * HIDDEN);
  float4 v = src[threadIdx.x];
  ushort4 o;
  o.x = f2bf(v.x); o.y = f2bf(v.y); o.z = f2bf(v.z); o.w = f2bf(v.w);
  ((ushort4*)(Xg + (size_t)r * HIDDEN))[threadIdx.x] = o;
}

// ---------------- transpose + fp32->bf16: in[E][R][C] -> out[E][C][R] ----------------
__global__ __launch_bounds__(256) void transpose_bf16_kernel(
    const float* __restrict__ in, unsigned short* __restrict__ out, int R, int C)
{
  __shared__ float tile[64][65];
  int e = blockIdx.z;
  int r0 = blockIdx.y * 64, c0 = blockIdx.x * 64;
  int tr = threadIdx.x >> 4, tc = threadIdx.x & 15;
  const float* src = in + ((size_t)e * R + r0) * C + c0;
#pragma unroll
  for (int rr = 0; rr < 4; rr++) {
    int row = rr * 16 + tr;
    float4 v = *(const float4*)(src + (size_t)row * C + tc * 4);
    tile[row][tc * 4 + 0] = v.x; tile[row][tc * 4 + 1] = v.y;
    tile[row][tc * 4 + 2] = v.z; tile[row][tc * 4 + 3] = v.w;
  }
  __syncthreads();
  unsigned short* dst = out + ((size_t)e * C + c0) * R + r0;
#pragma unroll
  for (int rr = 0; rr < 4; rr++) {
    int crow = rr * 16 + tr;
    ushort4 o;
    o.x = f2bf(tile[tc * 4 + 0][crow]);
    o.y = f2bf(tile[tc * 4 + 1][crow]);
    o.z = f2bf(tile[tc * 4 + 2][crow]);
    o.w = f2bf(tile[tc * 4 + 3][crow]);
    *(ushort4*)(dst + (size_t)crow * R + tc * 4) = o;
  }
}

// ---------------- m97-style bf16 GEMM, 128x128 tile, BK=32 ----------------
// EPI=0: H[local_row][N] = bf16(relu(acc + bias))        (A = Xg, global rows)
// EPI=1: atomicAdd(out[token][col], w*(acc + bias))      (A = H, local rows)
template<int EPI>
__global__ __launch_bounds__(256) void moe_gemm_kernel(
    const unsigned short* __restrict__ A,
    const unsigned short* __restrict__ Bt,   // [E][N][K] bf16
    const float* __restrict__ bias,          // [E][N]
    unsigned short* __restrict__ Hout,
    float* __restrict__ out,
    const int* __restrict__ meta,
    const int* __restrict__ pair_token,
    const float* __restrict__ pair_w,
    int K, int N, int tile_base)
{
  int ntiles = meta[25];
  int rt = tile_base + blockIdx.y;
  if (rt >= ntiles) return;
  int row0 = rt << 7;
  const int* offs = meta + 16;
  int e = 0;
  while (offs[e + 1] <= row0) e++;   // tiles never span experts (128-aligned)
  int ct = blockIdx.x;

  __shared__ __align__(16) unsigned short As[128 * 32];
  __shared__ __align__(16) unsigned short Bs[128 * 32];

  int tid = threadIdx.x;
  size_t a_row0 = (EPI == 0) ? (size_t)row0 : (size_t)(row0 - (tile_base << 7));
  const unsigned short* Ab = A + a_row0 * (size_t)K;
  const unsigned short* Bb = Bt + ((size_t)e * N + (size_t)ct * 128) * K;

  // staging: 512 chunks of 16B per tile; thread handles chunks tid and tid+256
  const unsigned short* ga0 = Ab + (size_t)(tid >> 2) * K + (tid & 3) * 8;
  const unsigned short* ga1 = ga0 + (size_t)64 * K;
  const unsigned short* gb0 = Bb + (size_t)(tid >> 2) * K + (tid & 3) * 8;
  const unsigned short* gb1 = gb0 + (size_t)64 * K;
  unsigned short* la0 = As + tid * 8;
  unsigned short* la1 = As + (tid + 256) * 8;
  unsigned short* lb0 = Bs + tid * 8;
  unsigned short* lb1 = Bs + (tid + 256) * 8;

  f32x4 acc[4][4];
  f32x4 zero = {0.f, 0.f, 0.f, 0.f};
#pragma unroll
  for (int i = 0; i < 4; i++)
#pragma unroll
    for (int j = 0; j < 4; j++) acc[i][j] = zero;

  int lane = tid & 63;
  int wv = tid >> 6;
  int wr = (wv >> 1) << 6;
  int wc = (wv & 1) << 6;
  int quad = lane >> 4;
  int l16 = lane & 15;
  const unsigned short* ar = As + (wr + l16) * 32 + quad * 8;
  const unsigned short* br = Bs + (wc + l16) * 32 + quad * 8;

  for (int k0 = 0; k0 < K; k0 += 32) {
    gld_lds16(ga0 + k0, la0);
    gld_lds16(ga1 + k0, la1);
    gld_lds16(gb0 + k0, lb0);
    gld_lds16(gb1 + k0, lb1);
    __syncthreads();
    short8 a[4], b[4];
#pragma unroll
    for (int mi = 0; mi < 4; mi++) a[mi] = *(const short8*)(ar + mi * 16 * 32);
#pragma unroll
    for (int ni = 0; ni < 4; ni++) b[ni] = *(const short8*)(br + ni * 16 * 32);
#pragma unroll
    for (int mi = 0; mi < 4; mi++)
#pragma unroll
      for (int ni = 0; ni < 4; ni++)
        acc[mi][ni] = __builtin_amdgcn_mfma_f32_16x16x32_bf16(
            a[mi], b[ni], acc[mi][ni], 0, 0, 0);
    __syncthreads();
  }

  if (EPI == 0) {
    size_t hbase = (size_t)(row0 - (tile_base << 7));
#pragma unroll
    for (int mi = 0; mi < 4; mi++) {
#pragma unroll
      for (int ni = 0; ni < 4; ni++) {
        int gcol = (ct << 7) + wc + ni * 16 + l16;
        float bb = bias[e * N + gcol];
#pragma unroll
        for (int j = 0; j < 4; j++) {
          int r = wr + mi * 16 + quad * 4 + j;   // C/D: row=quad*4+reg, col=lane&15
          float v = acc[mi][ni][j] + bb;
          v = fmaxf(v, 0.f);
          Hout[(hbase + r) * (size_t)N + gcol] = f2bf(v);
        }
      }
    }
  } else {
#pragma unroll
    for (int mi = 0; mi < 4; mi++) {
      int tok[4]; float wgt[4];
#pragma unroll
      for (int j = 0; j < 4; j++) {
        int r = row0 + wr + mi * 16 + quad * 4 + j;
        tok[j] = pair_token[r];
        wgt[j] = pair_w[r];
      }
#pragma unroll
      for (int ni = 0; ni < 4; ni++) {
        int gcol = (ct << 7) + wc + ni * 16 + l16;
        float bb = bias[e * N + gcol];
#pragma unroll
        for (int j = 0; j < 4; j++) {
          if (tok[j] >= 0)
            atomicAdd(out + (size_t)tok[j] * N + gcol,
                      wgt[j] * (acc[mi][ni][j] + bb));
        }
      }
    }
  }
}

extern "C" void kernel_launch(void* const* d_in, const int* in_sizes, int n_in,
                              void* d_out, int out_size, void* d_ws, size_t ws_size,
                              hipStream_t stream)
{
  const float* x  = (const float*)d_in[0];
  const float* Wg = (const float*)d_in[1];
  const float* bg = (const float*)d_in[2];
  const float* W1 = (const float*)d_in[3];
  const float* b1 = (const float*)d_in[4];
  const float* W2 = (const float*)d_in[5];
  const float* b2 = (const float*)d_in[6];
  float* out = (float*)d_out;

  // workspace carve-out (~344 MB total), 256B aligned chunks
  char* ws = (char*)d_ws;
  size_t off = 0;
  auto alloc = [&](size_t bytes) {
    char* p = ws + off;
    off += (bytes + 255) & ~(size_t)255;
    return p;
  };
  int* gate_idx          = (int*)alloc((size_t)N_TOKENS * 2 * sizeof(int));
  float* gate_w          = (float*)alloc((size_t)N_TOKENS * 2 * sizeof(float));
  int* meta              = (int*)alloc(256);
  int* pair_token        = (int*)alloc((size_t)MAX_ROWS * sizeof(int));
  float* pair_w          = (float*)alloc((size_t)MAX_ROWS * sizeof(float));
  unsigned short* Xg     = (unsigned short*)alloc((size_t)MAX_ROWS * HIDDEN * 2);
  unsigned short* W1T    = (unsigned short*)alloc((size_t)N_EXPERTS * FFN * HIDDEN * 2);
  unsigned short* W2T    = (unsigned short*)alloc((size_t)N_EXPERTS * HIDDEN * FFN * 2);
  unsigned short* H      = (unsigned short*)alloc((size_t)HALF_ROWS * FFN * 2);

  hipMemsetAsync(meta, 0, 256, stream);
  hipMemsetAsync(pair_token, 0xFF, (size_t)MAX_ROWS * sizeof(int), stream);  // -1
  hipMemsetAsync(out, 0, (size_t)N_TOKENS * HIDDEN * sizeof(float), stream);

  gate_kernel<<<N_TOKENS / 4, 256, 0, stream>>>(x, Wg, bg, gate_idx, gate_w, meta);
  offsets_kernel<<<1, 64, 0, stream>>>(meta);
  route_kernel<<<N_TOKENS / 256, 256, 0, stream>>>(gate_idx, gate_w, meta,
                                                   pair_token, pair_w);
  gather_kernel<<<MAX_ROWS, 256, 0, stream>>>(x, pair_token, Xg);
  transpose_bf16_kernel<<<dim3(FFN / 64, HIDDEN / 64, N_EXPERTS), 256, 0, stream>>>(
      W1, W1T, HIDDEN, FFN);
  transpose_bf16_kernel<<<dim3(HIDDEN / 64, FFN / 64, N_EXPERTS), 256, 0, stream>>>(
      W2, W2T, FFN, HIDDEN);

  for (int half = 0; half < 2; half++) {
    int tb = half * HALF_TILES;
    moe_gemm_kernel<0><<<dim3(FFN / 128, HALF_TILES), 256, 0, stream>>>(
        Xg, W1T, b1, H, nullptr, meta, nullptr, nullptr, HIDDEN, FFN, tb);
    moe_gemm_kernel<1><<<dim3(HIDDEN / 128, HALF_TILES), 256, 0, stream>>>(
        H, W2T, b2, nullptr, out, meta, pair_token, pair_w, FFN, HIDDEN, tb);
  }
}

// Round 2
// 1497.676 us; speedup vs baseline: 1.2382x; 1.2382x over previous
//
#include <hip/hip_runtime.h>
#include <stdint.h>

#define N_TOKENS 16384
#define HIDDEN   1024
#define FFN      4096
#define N_EXPERTS 8
#define NBLK     (N_TOKENS / 256)    // 64 routing blocks
#define MAX_TILES 264            // worst-case padded 128-row tiles (sum<=263)
#define HALF_TILES 132
#define MAX_ROWS (MAX_TILES * 128)   // 33792
#define HALF_ROWS (HALF_TILES * 128) // 16896

typedef __attribute__((ext_vector_type(8))) short short8;
typedef __attribute__((ext_vector_type(4))) float f32x4;

// meta layout (ints): [16..24] expert row offsets (128-aligned), [25] ntiles,
//                     [32..32+MAX_TILES) tile->expert map

__device__ inline unsigned short f2bf(float f) {
  union { float f; unsigned u; } c; c.f = f;
  unsigned u = c.u;
  unsigned r = (u + 0x7fffu + ((u >> 16) & 1u)) >> 16;  // RNE
  return (unsigned short)r;
}

__device__ inline void gld_lds16(const unsigned short* g, unsigned short* l) {
  __builtin_amdgcn_global_load_lds(
      (const __attribute__((address_space(1))) void*)g,
      (__attribute__((address_space(3))) void*)l, 16, 0, 0);
}

// ---------------- gate: scores, top-2, softmax (no atomics) ----------------
__global__ __launch_bounds__(256) void gate_kernel(
    const float* __restrict__ x, const float* __restrict__ Wg,
    const float* __restrict__ bg, int* __restrict__ gate_idx,
    float* __restrict__ gate_w)
{
  int lane = threadIdx.x & 63;
  int wv = threadIdx.x >> 6;
  int t = blockIdx.x * 4 + wv;
  const float* xr = x + (size_t)t * HIDDEN;
  float acc[N_EXPERTS];
#pragma unroll
  for (int e = 0; e < N_EXPERTS; e++) acc[e] = 0.f;
#pragma unroll
  for (int i = 0; i < HIDDEN / 64; i++) {
    int h = i * 64 + lane;
    float xv = xr[h];
    const float4* wv4 = (const float4*)(Wg + (size_t)h * N_EXPERTS);
    float4 w01 = wv4[0], w23 = wv4[1];
    acc[0] = fmaf(xv, w01.x, acc[0]); acc[1] = fmaf(xv, w01.y, acc[1]);
    acc[2] = fmaf(xv, w01.z, acc[2]); acc[3] = fmaf(xv, w01.w, acc[3]);
    acc[4] = fmaf(xv, w23.x, acc[4]); acc[5] = fmaf(xv, w23.y, acc[5]);
    acc[6] = fmaf(xv, w23.z, acc[6]); acc[7] = fmaf(xv, w23.w, acc[7]);
  }
#pragma unroll
  for (int off = 32; off > 0; off >>= 1)
#pragma unroll
    for (int e = 0; e < N_EXPERTS; e++)
      acc[e] += __shfl_down(acc[e], off, 64);
  if (lane == 0) {
    float s[N_EXPERTS];
#pragma unroll
    for (int e = 0; e < N_EXPERTS; e++) s[e] = acc[e] + bg[e];
    int e0 = 0;
#pragma unroll
    for (int e = 1; e < N_EXPERTS; e++) if (s[e] > s[e0]) e0 = e;  // ties -> lowest idx
    int e1 = (e0 == 0) ? 1 : 0;
#pragma unroll
    for (int e = 0; e < N_EXPERTS; e++) if (e != e0 && s[e] > s[e1]) e1 = e;
    float d = s[e1] - s[e0];          // <= 0
    float ex = __expf(d);
    float w0 = 1.f / (1.f + ex);
    float w1 = ex / (1.f + ex);
    gate_idx[2 * t] = e0; gate_idx[2 * t + 1] = e1;
    gate_w[2 * t] = w0;  gate_w[2 * t + 1] = w1;
  }
}

// ---------------- per-block expert histogram (LDS atomics only) ----------------
__global__ __launch_bounds__(256) void count_kernel(
    const int* __restrict__ gate_idx, int* __restrict__ blockCounts)
{
  __shared__ int h[N_EXPERTS];
  if (threadIdx.x < N_EXPERTS) h[threadIdx.x] = 0;
  __syncthreads();
  int t = blockIdx.x * 256 + threadIdx.x;
  atomicAdd(&h[gate_idx[2 * t]], 1);
  atomicAdd(&h[gate_idx[2 * t + 1]], 1);
  __syncthreads();
  if (threadIdx.x < N_EXPERTS)
    blockCounts[blockIdx.x * N_EXPERTS + threadIdx.x] = h[threadIdx.x];
}

// ---------------- scan: block bases, 128-aligned offsets, tile->expert ----------------
__global__ void scan_kernel(const int* __restrict__ blockCounts,
                            int* __restrict__ blockBase, int* __restrict__ meta)
{
  __shared__ int totals[N_EXPERTS];
  __shared__ int offs[N_EXPERTS + 1];
  int e = threadIdx.x;
  if (e < N_EXPERTS) {
    int run = 0;
    for (int b = 0; b < NBLK; b++) {
      blockBase[b * N_EXPERTS + e] = run;
      run += blockCounts[b * N_EXPERTS + e];
    }
    totals[e] = run;
  }
  __syncthreads();
  if (threadIdx.x == 0) {
    int off = 0;
    for (int ee = 0; ee < N_EXPERTS; ee++) {
      offs[ee] = off;
      meta[16 + ee] = off;
      off += ((totals[ee] + 127) >> 7) << 7;
    }
    offs[N_EXPERTS] = off;
    meta[16 + N_EXPERTS] = off;
    int ntiles = off >> 7;
    meta[25] = ntiles;
    int ee = 0;
    for (int t = 0; t < ntiles; t++) {
      while (offs[ee + 1] <= (t << 7)) ee++;
      meta[32 + t] = ee;
    }
  }
  __syncthreads();
  if (e < N_EXPERTS) {
    int o = offs[e];
    for (int b = 0; b < NBLK; b++)
      blockBase[b * N_EXPERTS + e] += o;
  }
}

// ---------------- place: slot assignment via LDS cursors ----------------
__global__ __launch_bounds__(256) void place_kernel(
    const int* __restrict__ gate_idx, const float* __restrict__ gate_w,
    const int* __restrict__ blockBase, int* __restrict__ pair_token,
    float* __restrict__ pair_w)
{
  __shared__ int cur[N_EXPERTS];
  if (threadIdx.x < N_EXPERTS)
    cur[threadIdx.x] = blockBase[blockIdx.x * N_EXPERTS + threadIdx.x];
  __syncthreads();
  int t = blockIdx.x * 256 + threadIdx.x;
#pragma unroll
  for (int k = 0; k < 2; k++) {
    int e = gate_idx[2 * t + k];
    int pos = atomicAdd(&cur[e], 1);   // LDS atomic
    pair_token[pos] = t;
    pair_w[pos] = gate_w[2 * t + k];
  }
}

// ---------------- gather x rows -> bf16 Xg (grouped rows) ----------------
__global__ __launch_bounds__(256) void gather_kernel(
    const float* __restrict__ x, const int* __restrict__ pair_token,
    unsigned short* __restrict__ Xg)
{
  int r = blockIdx.x;
  int t = pair_token[r];
  if (t < 0) return;  // pad row: left as poison; dropped at GEMM2 epilogue
  const float4* src = (const float4*)(x + (size_t)t * HIDDEN);
  float4 v = src[threadIdx.x];
  ushort4 o;
  o.x = f2bf(v.x); o.y = f2bf(v.y); o.z = f2bf(v.z); o.w = f2bf(v.w);
  ((ushort4*)(Xg + (size_t)r * HIDDEN))[threadIdx.x] = o;
}

// ---------------- transpose + fp32->bf16: in[E][R][C] -> out[E][C][R] ----------------
__global__ __launch_bounds__(256) void transpose_bf16_kernel(
    const float* __restrict__ in, unsigned short* __restrict__ out, int R, int C)
{
  __shared__ float tile[64][65];
  int e = blockIdx.z;
  int r0 = blockIdx.y * 64, c0 = blockIdx.x * 64;
  int tr = threadIdx.x >> 4, tc = threadIdx.x & 15;
  const float* src = in + ((size_t)e * R + r0) * C + c0;
#pragma unroll
  for (int rr = 0; rr < 4; rr++) {
    int row = rr * 16 + tr;
    float4 v = *(const float4*)(src + (size_t)row * C + tc * 4);
    tile[row][tc * 4 + 0] = v.x; tile[row][tc * 4 + 1] = v.y;
    tile[row][tc * 4 + 2] = v.z; tile[row][tc * 4 + 3] = v.w;
  }
  __syncthreads();
  unsigned short* dst = out + ((size_t)e * C + c0) * R + r0;
#pragma unroll
  for (int rr = 0; rr < 4; rr++) {
    int crow = rr * 16 + tr;
    ushort4 o;
    o.x = f2bf(tile[tc * 4 + 0][crow]);
    o.y = f2bf(tile[tc * 4 + 1][crow]);
    o.z = f2bf(tile[tc * 4 + 2][crow]);
    o.w = f2bf(tile[tc * 4 + 3][crow]);
    *(ushort4*)(dst + (size_t)crow * R + tc * 4) = o;
  }
}

// ---------------- m97-style bf16 GEMM, 128x128 tile, BK=32 ----------------
// EPI=0: H[local_row][N] = bf16(relu(acc + bias))        (A = Xg, global rows)
// EPI=1: atomicAdd(out[token][col], w*(acc + bias))      (A = H, local rows)
template<int EPI>
__global__ __launch_bounds__(256) void moe_gemm_kernel(
    const unsigned short* __restrict__ A,
    const unsigned short* __restrict__ Bt,   // [E][N][K] bf16
    const float* __restrict__ bias,          // [E][N]
    unsigned short* __restrict__ Hout,
    float* __restrict__ out,
    const int* __restrict__ meta,
    const int* __restrict__ pair_token,
    const float* __restrict__ pair_w,
    int K, int N, int tile_base)
{
  int ntiles = meta[25];
  int rt = tile_base + blockIdx.y;
  if (rt >= ntiles) return;
  int row0 = rt << 7;
  int e = meta[32 + rt];               // precomputed tile->expert
  int ct = blockIdx.x;

  __shared__ __align__(16) unsigned short As[128 * 32];
  __shared__ __align__(16) unsigned short Bs[128 * 32];

  int tid = threadIdx.x;
  size_t a_row0 = (EPI == 0) ? (size_t)row0 : (size_t)(row0 - (tile_base << 7));
  const unsigned short* Ab = A + a_row0 * (size_t)K;
  const unsigned short* Bb = Bt + ((size_t)e * N + (size_t)ct * 128) * K;

  // staging: 512 chunks of 16B per tile; thread handles chunks tid and tid+256
  const unsigned short* ga0 = Ab + (size_t)(tid >> 2) * K + (tid & 3) * 8;
  const unsigned short* ga1 = ga0 + (size_t)64 * K;
  const unsigned short* gb0 = Bb + (size_t)(tid >> 2) * K + (tid & 3) * 8;
  const unsigned short* gb1 = gb0 + (size_t)64 * K;
  unsigned short* la0 = As + tid * 8;
  unsigned short* la1 = As + (tid + 256) * 8;
  unsigned short* lb0 = Bs + tid * 8;
  unsigned short* lb1 = Bs + (tid + 256) * 8;

  f32x4 acc[4][4];
  f32x4 zero = {0.f, 0.f, 0.f, 0.f};
#pragma unroll
  for (int i = 0; i < 4; i++)
#pragma unroll
    for (int j = 0; j < 4; j++) acc[i][j] = zero;

  int lane = tid & 63;
  int wv = tid >> 6;
  int wr = (wv >> 1) << 6;
  int wc = (wv & 1) << 6;
  int quad = lane >> 4;
  int l16 = lane & 15;
  const unsigned short* ar = As + (wr + l16) * 32 + quad * 8;
  const unsigned short* br = Bs + (wc + l16) * 32 + quad * 8;

  for (int k0 = 0; k0 < K; k0 += 32) {
    gld_lds16(ga0 + k0, la0);
    gld_lds16(ga1 + k0, la1);
    gld_lds16(gb0 + k0, lb0);
    gld_lds16(gb1 + k0, lb1);
    __syncthreads();
    short8 a[4], b[4];
#pragma unroll
    for (int mi = 0; mi < 4; mi++) a[mi] = *(const short8*)(ar + mi * 16 * 32);
#pragma unroll
    for (int ni = 0; ni < 4; ni++) b[ni] = *(const short8*)(br + ni * 16 * 32);
#pragma unroll
    for (int mi = 0; mi < 4; mi++)
#pragma unroll
      for (int ni = 0; ni < 4; ni++)
        acc[mi][ni] = __builtin_amdgcn_mfma_f32_16x16x32_bf16(
            a[mi], b[ni], acc[mi][ni], 0, 0, 0);
    __syncthreads();
  }

  if (EPI == 0) {
    size_t hbase = (size_t)(row0 - (tile_base << 7));
#pragma unroll
    for (int mi = 0; mi < 4; mi++) {
#pragma unroll
      for (int ni = 0; ni < 4; ni++) {
        int gcol = (ct << 7) + wc + ni * 16 + l16;
        float bb = bias[e * N + gcol];
#pragma unroll
        for (int j = 0; j < 4; j++) {
          int r = wr + mi * 16 + quad * 4 + j;   // C/D: row=quad*4+reg, col=lane&15
          float v = acc[mi][ni][j] + bb;
          v = fmaxf(v, 0.f);
          Hout[(hbase + r) * (size_t)N + gcol] = f2bf(v);
        }
      }
    }
  } else {
#pragma unroll
    for (int mi = 0; mi < 4; mi++) {
      int tok[4]; float wgt[4];
#pragma unroll
      for (int j = 0; j < 4; j++) {
        int r = row0 + wr + mi * 16 + quad * 4 + j;
        tok[j] = pair_token[r];
        wgt[j] = pair_w[r];
      }
#pragma unroll
      for (int ni = 0; ni < 4; ni++) {
        int gcol = (ct << 7) + wc + ni * 16 + l16;
        float bb = bias[e * N + gcol];
#pragma unroll
        for (int j = 0; j < 4; j++) {
          if (tok[j] >= 0)
            atomicAdd(out + (size_t)tok[j] * N + gcol,
                      wgt[j] * (acc[mi][ni][j] + bb));
        }
      }
    }
  }
}

extern "C" void kernel_launch(void* const* d_in, const int* in_sizes, int n_in,
                              void* d_out, int out_size, void* d_ws, size_t ws_size,
                              hipStream_t stream)
{
  const float* x  = (const float*)d_in[0];
  const float* Wg = (const float*)d_in[1];
  const float* bg = (const float*)d_in[2];
  const float* W1 = (const float*)d_in[3];
  const float* b1 = (const float*)d_in[4];
  const float* W2 = (const float*)d_in[5];
  const float* b2 = (const float*)d_in[6];
  float* out = (float*)d_out;

  // workspace carve-out (~344 MB total), 256B aligned chunks
  char* ws = (char*)d_ws;
  size_t off = 0;
  auto alloc = [&](size_t bytes) {
    char* p = ws + off;
    off += (bytes + 255) & ~(size_t)255;
    return p;
  };
  int* gate_idx          = (int*)alloc((size_t)N_TOKENS * 2 * sizeof(int));
  float* gate_w          = (float*)alloc((size_t)N_TOKENS * 2 * sizeof(float));
  int* meta              = (int*)alloc(2048);
  int* blockCounts       = (int*)alloc((size_t)NBLK * N_EXPERTS * sizeof(int));
  int* blockBase         = (int*)alloc((size_t)NBLK * N_EXPERTS * sizeof(int));
  int* pair_token        = (int*)alloc((size_t)MAX_ROWS * sizeof(int));
  float* pair_w          = (float*)alloc((size_t)MAX_ROWS * sizeof(float));
  unsigned short* Xg     = (unsigned short*)alloc((size_t)MAX_ROWS * HIDDEN * 2);
  unsigned short* W1T    = (unsigned short*)alloc((size_t)N_EXPERTS * FFN * HIDDEN * 2);
  unsigned short* W2T    = (unsigned short*)alloc((size_t)N_EXPERTS * HIDDEN * FFN * 2);
  unsigned short* H      = (unsigned short*)alloc((size_t)HALF_ROWS * FFN * 2);

  hipMemsetAsync(pair_token, 0xFF, (size_t)MAX_ROWS * sizeof(int), stream);  // -1
  hipMemsetAsync(out, 0, (size_t)N_TOKENS * HIDDEN * sizeof(float), stream);

  gate_kernel<<<N_TOKENS / 4, 256, 0, stream>>>(x, Wg, bg, gate_idx, gate_w);
  count_kernel<<<NBLK, 256, 0, stream>>>(gate_idx, blockCounts);
  scan_kernel<<<1, 64, 0, stream>>>(blockCounts, blockBase, meta);
  place_kernel<<<NBLK, 256, 0, stream>>>(gate_idx, gate_w, blockBase,
                                         pair_token, pair_w);
  gather_kernel<<<MAX_ROWS, 256, 0, stream>>>(x, pair_token, Xg);
  transpose_bf16_kernel<<<dim3(FFN / 64, HIDDEN / 64, N_EXPERTS), 256, 0, stream>>>(
      W1, W1T, HIDDEN, FFN);
  transpose_bf16_kernel<<<dim3(HIDDEN / 64, FFN / 64, N_EXPERTS), 256, 0, stream>>>(
      W2, W2T, FFN, HIDDEN);

  for (int half = 0; half < 2; half++) {
    int tb = half * HALF_TILES;
    moe_gemm_kernel<0><<<dim3(FFN / 128, HALF_TILES), 256, 0, stream>>>(
        Xg, W1T, b1, H, nullptr, meta, nullptr, nullptr, HIDDEN, FFN, tb);
    moe_gemm_kernel<1><<<dim3(HIDDEN / 128, HALF_TILES), 256, 0, stream>>>(
        H, W2T, b2, nullptr, out, meta, pair_token, pair_w, FFN, HIDDEN, tb);
  }
}